// Round 3
// baseline (579.642 us; speedup 1.0000x reference)
//
#include <hip/hip_runtime.h>

#define DIMN 2048
#define RANKN 128
#define TT 1024
#define BBATCH 16
#define BD (BBATCH * DIMN)   // 32768 elements per timestep slice
#define CH 16                // scan chunk length (t-steps)
#define PADW 68              // LDS row pitch in floats (2-way max on all patterns)

typedef __attribute__((ext_vector_type(4))) float floatx4;
typedef __attribute__((ext_vector_type(8))) short short8;

// fp32 -> bf16 round-to-nearest-even on raw bits
__device__ __forceinline__ short f2bf(float f) {
    unsigned u = __float_as_uint(f);
    unsigned r = (u + 0x7FFFu + ((u >> 16) & 1u)) >> 16;
    return (short)r;
}
__device__ __forceinline__ float fast_sigmoid(float z) {
    return 1.0f / (1.0f + __expf(-z));
}
__device__ __forceinline__ float fast_tanh(float z) {
    return 1.0f - 2.0f / (__expf(2.0f * z) + 1.0f);
}

// ---------------------------------------------------------------------------
// Prep: V_x|V_d -> bf16 Vb[256][2048] (rows 0..127 = V_x, 128..255 = V_d).
// ---------------------------------------------------------------------------
__global__ __launch_bounds__(256)
void prep_vb(const float* __restrict__ Vx, const float* __restrict__ Vd,
             short* __restrict__ Vb) {
    const int gid = blockIdx.x * 256 + threadIdx.x;     // 0..65535
    const size_t base = (size_t)gid * 8;
    const size_t half = (size_t)RANKN * DIMN;           // 262144
    const float* src = (base < half) ? Vx : Vd;
    const size_t off = (base < half) ? base : (base - half);
    float4 a = *(const float4*)(src + off);
    float4 c = *(const float4*)(src + off + 4);
    short8 v;
    v[0] = f2bf(a.x); v[1] = f2bf(a.y); v[2] = f2bf(a.z); v[3] = f2bf(a.w);
    v[4] = f2bf(c.x); v[5] = f2bf(c.y); v[6] = f2bf(c.z); v[7] = f2bf(c.w);
    *(short8*)(Vb + base) = v;
}

// ---------------------------------------------------------------------------
// Phase 1: xvb[16384][256] = x @ [V_x^T | V_d^T] (bf16 out).
// LDS-FREE, BARRIER-FREE GEMM. One 64-thread wave per block, M=32 rows/wave,
// full N=256, grid 512 = 2 blocks/CU.
//   A-frag (16x16x32 layout: lane row=lr, k=q*8..+8): 8 consecutive fp32 of
//     one x row -> 2x float4 global load + inline f2bf.
//   B-frag (lane col=lr, k=q*8..+8): 8 consecutive bf16 of one Vb row ->
//     one short8 global load (Vb is 1 MB, L2-resident).
// Depth-2 K-step register prefetch (sets A/B, named statically per rule #20);
// no __syncthreads anywhere -> compiler free to hoist loads across MFMAs.
// Accumulation order over k identical to previous passing version.
// ---------------------------------------------------------------------------
__global__ __launch_bounds__(64, 1)
void gemm_xv(const float* __restrict__ X, const short* __restrict__ Vb,
             short* __restrict__ xvb) {
    const int lane = threadIdx.x;
    const int lr = lane & 15;
    const int q  = lane >> 4;
    const int m0 = blockIdx.x * 32;

    const float* ap = X  + (size_t)(m0 + lr) * DIMN + q * 8;
    const short* bp = Vb + (size_t)lr * DIMN + q * 8;

    floatx4 acc[2][16] = {};
    float4 aA[2][2], aB[2][2];
    short8 bA[16], bB[16];

    // prologue: set A <- k=0, set B <- k=32
    #pragma unroll
    for (int mi = 0; mi < 2; ++mi) {
        const float* am = ap + (size_t)mi * 16 * DIMN;
        aA[mi][0] = *(const float4*)(am);
        aA[mi][1] = *(const float4*)(am + 4);
        aB[mi][0] = *(const float4*)(am + 32);
        aB[mi][1] = *(const float4*)(am + 36);
    }
    #pragma unroll
    for (int nj = 0; nj < 16; ++nj) {
        const short* bn = bp + (size_t)nj * 16 * DIMN;
        bA[nj] = *(const short8*)(bn);
        bB[nj] = *(const short8*)(bn + 32);
    }

    auto step = [&](float4 (&xa)[2][2], short8 (&bset)[16], int knext, bool pf) {
        short8 af[2];
        #pragma unroll
        for (int mi = 0; mi < 2; ++mi) {
            af[mi][0] = f2bf(xa[mi][0].x); af[mi][1] = f2bf(xa[mi][0].y);
            af[mi][2] = f2bf(xa[mi][0].z); af[mi][3] = f2bf(xa[mi][0].w);
            af[mi][4] = f2bf(xa[mi][1].x); af[mi][5] = f2bf(xa[mi][1].y);
            af[mi][6] = f2bf(xa[mi][1].z); af[mi][7] = f2bf(xa[mi][1].w);
            if (pf) {
                const float* am = ap + (size_t)mi * 16 * DIMN + knext;
                xa[mi][0] = *(const float4*)(am);
                xa[mi][1] = *(const float4*)(am + 4);
            }
        }
        #pragma unroll
        for (int nj = 0; nj < 16; ++nj) {
            short8 bv = bset[nj];
            if (pf) bset[nj] = *(const short8*)(bp + (size_t)nj * 16 * DIMN + knext);
            #pragma unroll
            for (int mi = 0; mi < 2; ++mi)
                acc[mi][nj] = __builtin_amdgcn_mfma_f32_16x16x32_bf16(
                    af[mi], bv, acc[mi][nj], 0, 0, 0);
        }
    };

    for (int k0 = 0; k0 < DIMN; k0 += 64) {
        step(aA, bA, k0 + 64, k0 + 64 < DIMN);
        step(aB, bB, k0 + 96, k0 + 96 < DIMN);
    }

    // C/D layout: col=lane&15, row=(lane>>4)*4+reg (m89-verified)
    #pragma unroll
    for (int mi = 0; mi < 2; ++mi) {
        short* cp = xvb + (size_t)(m0 + mi * 16 + q * 4) * 256 + lr;
        #pragma unroll
        for (int nj = 0; nj < 16; ++nj)
            #pragma unroll
            for (int r = 0; r < 4; ++r)
                cp[(size_t)r * 256 + nj * 16] = f2bf(acc[mi][nj][r]);
    }
}

// ---------------------------------------------------------------------------
// Phase 2+3 fused, 3-stage pipeline, now 2 blocks/CU for barrier overlap.
// Grid 512 = (32 d-chunks of 64) x 16 b, XCD-swizzled (2 b per XCD -> the
// xvb b-slices this XCD reads are ~1 MB, L2-resident). Block = 128 threads:
//   wave 0 (producer+flusher): MFMA-fill wx/wd[chunk i] (n=64 wide) into LDS
//     buf i&1; prefetch xvb frags (i+1) and x (i-1); flush chunk i-2
//     (gate + coalesced dwordx4 stores).
//   wave 1 (consumer): scan chunk i-1: 64 chains (1/lane), pure VALU + LDS.
// Parities identical to the proven v1 scheme (fill i&1, consumer (i-1)&1,
// flusher reads hs[i&1] written at iter i-1). One barrier per iter; while
// this block drains stores at the barrier, the co-resident block computes.
// LDS: 3 arrays x 2 bufs x 16 x 68 floats = 25.5 KB/block.
// ---------------------------------------------------------------------------
__global__ __launch_bounds__(128, 1)
void fused_scan(const short* __restrict__ xvb, const float* __restrict__ x,
                const float* __restrict__ h0,
                const float* __restrict__ Ux, const float* __restrict__ Ud,
                const float* __restrict__ r_h, const float* __restrict__ r_delta,
                const float* __restrict__ bvec, const float* __restrict__ b_delta,
                const float* __restrict__ b_gate,
                float* __restrict__ obuf, float* __restrict__ hbuf) {
    __shared__ float wxs[2][CH * PADW];
    __shared__ float wds[2][CH * PADW];
    __shared__ float hs [2][CH * PADW];

    const int id   = blockIdx.x;        // 0..511
    const int xcd  = id & 7;
    const int slot = id >> 3;           // 0..63
    const int b  = xcd * 2 + (slot & 1);
    const int d0 = (slot >> 1) * 64;

    const int tid  = threadIdx.x;
    const int wave = tid >> 6;
    const int lane = tid & 63;
    const int lr = lane & 15;
    const int q  = lane >> 4;

    // consumer geometry (wave 1): one chain per lane
    const int d = d0 + lane;
    const size_t xoff = (size_t)b * DIMN + d;
    // flusher geometry (wave 0)
    const int dq  = lane & 15;
    const int tof = lane >> 4;
    const size_t xoffF = (size_t)b * DIMN + d0 + dq * 4;

    short8 uf[2][4][4];                 // U fragments [mat][nj][ks]
    short8 afp[2][4], afn[2][4];        // xvb A-frag double buffer
    float4 xpre[4], xnew[4];            // flusher x prefetch (one iter ahead)
    float4 bg4 = {};
    float h = 0.f, rh = 0.f, rd = 0.f, bb = 0.f, bdl = 0.f;

    if (wave == 0) {
        // one-time U fragment load + convert (B-operand layout)
        #pragma unroll
        for (int mat = 0; mat < 2; ++mat) {
            const float* Up = mat ? Ud : Ux;
            #pragma unroll
            for (int nj = 0; nj < 4; ++nj) {
                const size_t dd = (size_t)(d0 + nj * 16 + lr);
                #pragma unroll
                for (int ks = 0; ks < 4; ++ks) {
                    const int k = ks * 32 + q * 8;
                    float4 u0 = *(const float4*)&Up[dd * RANKN + k];
                    float4 u1 = *(const float4*)&Up[dd * RANKN + k + 4];
                    short8 v;
                    v[0] = f2bf(u0.x); v[1] = f2bf(u0.y);
                    v[2] = f2bf(u0.z); v[3] = f2bf(u0.w);
                    v[4] = f2bf(u1.x); v[5] = f2bf(u1.y);
                    v[6] = f2bf(u1.z); v[7] = f2bf(u1.w);
                    uf[mat][nj][ks] = v;
                }
            }
        }
        // prefetch xvb fragments for chunk 0 (A row m = t*BBATCH + b)
        {
            const size_t row = (size_t)lr * BBATCH + b;
            #pragma unroll
            for (int mat = 0; mat < 2; ++mat)
                #pragma unroll
                for (int ks = 0; ks < 4; ++ks)
                    afp[mat][ks] = *(const short8*)
                        &xvb[row * 256 + mat * RANKN + ks * 32 + q * 8];
        }
        bg4 = *(const float4*)&b_gate[d0 + dq * 4];
    } else {
        rh  = r_h[d];  rd  = r_delta[d];
        bb  = bvec[d]; bdl = b_delta[d];
        h = h0[xoff];
        hbuf[xoff] = h;                 // h[0] = h0
    }

    for (int i = 0; i < 66; ++i) {
        if (wave == 0) {
            // ---- fill chunk i (MFMA on prefetched frags)
            if (i < 64) {
                const int pb = i & 1;
                #pragma unroll
                for (int mat = 0; mat < 2; ++mat) {
                    float* outp = mat ? wds[pb] : wxs[pb];
                    #pragma unroll
                    for (int nj = 0; nj < 4; ++nj) {
                        floatx4 acc = {};
                        #pragma unroll
                        for (int ks = 0; ks < 4; ++ks)
                            acc = __builtin_amdgcn_mfma_f32_16x16x32_bf16(
                                afp[mat][ks], uf[mat][nj][ks], acc, 0, 0, 0);
                        #pragma unroll
                        for (int r = 0; r < 4; ++r)
                            outp[(q * 4 + r) * PADW + nj * 16 + lr] = acc[r];
                    }
                }
            }
            // ---- prefetch xvb frags for chunk i+1
            if (i < 63) {
                const size_t row = (size_t)((i + 1) * CH + lr) * BBATCH + b;
                #pragma unroll
                for (int mat = 0; mat < 2; ++mat)
                    #pragma unroll
                    for (int ks = 0; ks < 4; ++ks)
                        afn[mat][ks] = *(const short8*)
                            &xvb[row * 256 + mat * RANKN + ks * 32 + q * 8];
            }
            // ---- prefetch x for chunk i-1 (flushed next iter)
            if (i >= 1 && i < 65) {
                const int tb = (i - 1) * CH;
                #pragma unroll
                for (int jj = 0; jj < 4; ++jj)
                    xnew[jj] = *(const float4*)
                        &x[(size_t)(tb + jj * 4 + tof) * BD + xoffF];
            }
            // ---- flush chunk i-2: out = h*silu(h+x+bg), h -> hbuf
            if (i >= 2) {
                const int j = i - 2;
                const int fb = j & 1;
                const int tb = j * CH;
                #pragma unroll
                for (int jj = 0; jj < 4; ++jj) {
                    const int t = jj * 4 + tof;
                    const float4 hv = *(const float4*)&hs[fb][t * PADW + dq * 4];
                    const float4 xv = xpre[jj];
                    float4 ov;
                    {
                        float g0 = hv.x + xv.x + bg4.x;
                        ov.x = hv.x * (g0 * fast_sigmoid(g0));
                        float g1 = hv.y + xv.y + bg4.y;
                        ov.y = hv.y * (g1 * fast_sigmoid(g1));
                        float g2 = hv.z + xv.z + bg4.z;
                        ov.z = hv.z * (g2 * fast_sigmoid(g2));
                        float g3 = hv.w + xv.w + bg4.w;
                        ov.w = hv.w * (g3 * fast_sigmoid(g3));
                    }
                    *(float4*)&obuf[(size_t)(tb + t) * BD + xoffF] = ov;
                    *(float4*)&hbuf[(size_t)(tb + t + 1) * BD + xoffF] = hv;
                }
            }
            // ---- rotate prefetch registers
            if (i < 63) {
                #pragma unroll
                for (int mat = 0; mat < 2; ++mat)
                    #pragma unroll
                    for (int ks = 0; ks < 4; ++ks)
                        afp[mat][ks] = afn[mat][ks];
            }
            if (i >= 1 && i < 65) {
                #pragma unroll
                for (int jj = 0; jj < 4; ++jj)
                    xpre[jj] = xnew[jj];
            }
        } else if (i >= 1 && i < 65) {
            // ---- consumer: scan chunk i-1 (pure VALU + LDS; no vmem)
            const int pb = (i - 1) & 1;
            float wxr[CH], wdr[CH];
            #pragma unroll
            for (int s = 0; s < CH; ++s) {
                wxr[s] = wxs[pb][s * PADW + lane];
                wdr[s] = wds[pb][s * PADW + lane];
            }
            #pragma unroll
            for (int s = 0; s < CH; ++s) {
                const float cand  = fast_tanh(rh * h + wxr[s] + bb);
                const float delta = fast_sigmoid(wdr[s] + rd * h + bdl);
                h = (1.0f - delta) * h + delta * cand;
                hs[pb][s * PADW + lane] = h;
            }
        }
        __syncthreads();
    }
}

// ---------------------------------------------------------------------------
extern "C" void kernel_launch(void* const* d_in, const int* in_sizes, int n_in,
                              void* d_out, int out_size, void* d_ws, size_t ws_size,
                              hipStream_t stream) {
    const float* x       = (const float*)d_in[0];   // [T,B,D]
    const float* h0      = (const float*)d_in[1];   // [B,D]
    const float* U_x     = (const float*)d_in[2];   // [D,R]
    const float* V_x     = (const float*)d_in[3];   // [R,D]
    const float* U_d     = (const float*)d_in[4];   // [D,R]
    const float* V_d     = (const float*)d_in[5];   // [R,D]
    const float* r_h     = (const float*)d_in[6];
    const float* r_delta = (const float*)d_in[7];
    const float* bvec    = (const float*)d_in[8];
    const float* b_delta = (const float*)d_in[9];
    const float* b_gate  = (const float*)d_in[10];

    float* obuf = (float*)d_out;                    // output [T,B,D]
    float* hbuf = obuf + (size_t)TT * BD;           // h [T+1,B,D]
    short* xvb  = (short*)d_ws;                     // bf16 [16384][256]: xv|xd
    short* Vb   = xvb + (size_t)TT * BBATCH * 256;  // bf16 [256][2048]

    // Phase 0: one-time V -> bf16
    prep_vb<<<256, 256, 0, stream>>>(V_x, V_d, Vb);

    // Phase 1: LDS-free low-rank projections (x read once).
    gemm_xv<<<TT * BBATCH / 32, 64, 0, stream>>>(x, Vb, xvb);

    // Phase 2+3: producer/consumer/flusher fused GEMM + scan + gate.
    fused_scan<<<512, 128, 0, stream>>>(xvb, x, h0, U_x, U_d,
                                        r_h, r_delta, bvec, b_delta, b_gate,
                                        obuf, hbuf);
}

// Round 4
// 576.507 us; speedup vs baseline: 1.0054x; 1.0054x over previous
//
#include <hip/hip_runtime.h>

#define DIMN 2048
#define RANKN 128
#define TT 1024
#define BBATCH 16
#define BD (BBATCH * DIMN)   // 32768 elements per timestep slice
#define CH 16                // scan chunk length (t-steps)
#define PADW 68              // LDS row pitch in floats (<=2-way on all patterns)

typedef __attribute__((ext_vector_type(4))) float floatx4;
typedef __attribute__((ext_vector_type(8))) short short8;

// fp32 -> bf16 round-to-nearest-even on raw bits
__device__ __forceinline__ short f2bf(float f) {
    unsigned u = __float_as_uint(f);
    unsigned r = (u + 0x7FFFu + ((u >> 16) & 1u)) >> 16;
    return (short)r;
}
__device__ __forceinline__ float fast_sigmoid(float z) {
    return 1.0f / (1.0f + __expf(-z));
}
__device__ __forceinline__ float fast_tanh(float z) {
    return 1.0f - 2.0f / (__expf(2.0f * z) + 1.0f);
}

// ---------------------------------------------------------------------------
// Prep: V_x|V_d -> bf16 Vb[256][2048] (rows 0..127 = V_x, 128..255 = V_d).
// ---------------------------------------------------------------------------
__global__ __launch_bounds__(256)
void prep_vb(const float* __restrict__ Vx, const float* __restrict__ Vd,
             short* __restrict__ Vb) {
    const int gid = blockIdx.x * 256 + threadIdx.x;     // 0..65535
    const size_t base = (size_t)gid * 8;
    const size_t half = (size_t)RANKN * DIMN;           // 262144
    const float* src = (base < half) ? Vx : Vd;
    const size_t off = (base < half) ? base : (base - half);
    float4 a = *(const float4*)(src + off);
    float4 c = *(const float4*)(src + off + 4);
    short8 v;
    v[0] = f2bf(a.x); v[1] = f2bf(a.y); v[2] = f2bf(a.z); v[3] = f2bf(a.w);
    v[4] = f2bf(c.x); v[5] = f2bf(c.y); v[6] = f2bf(c.z); v[7] = f2bf(c.w);
    *(short8*)(Vb + base) = v;
}

// ---------------------------------------------------------------------------
// Phase 1: xvb = x @ [V_x^T | V_d^T] as bf16 [16384][256]. (R2 version,
// measured faster than the LDS-free R3 variant by ~30 us.)
// M-tile 32 -> 512 blocks = 2 blocks/CU. 4 waves: (mat = wave>>1,
// n-half = (wave&1)*64); acc[2 mi][4 nj].
// ---------------------------------------------------------------------------
__global__ __launch_bounds__(256, 2)
void gemm_xv(const float* __restrict__ X, const short* __restrict__ Vb,
             short* __restrict__ xvb) {
    constexpr int PADK = 40;            // proven conflict-free (80 B, 16-B mult)
    __shared__ short As[32 * PADK];
    __shared__ short Bs[2][128 * PADK];

    const int m0 = blockIdx.x * 32;
    const int tid = threadIdx.x;
    const int wave = tid >> 6;
    const int lane = tid & 63;
    const int lr = lane & 15;
    const int q  = lane >> 4;
    const int mat = wave >> 1;
    const int wn  = (wave & 1) * 64;

    floatx4 acc[2][4] = {};

    for (int k0 = 0; k0 < DIMN; k0 += 32) {
        // A: 32x32 fp32 -> bf16 (1 float4/thread)
        {
            int r = tid >> 3, c = (tid & 7) * 4;
            float4 v = *(const float4*)(X + (size_t)(m0 + r) * DIMN + k0 + c);
            *(short4*)&As[r * PADK + c] =
                make_short4(f2bf(v.x), f2bf(v.y), f2bf(v.z), f2bf(v.w));
        }
        // B: 2x128x32 bf16 copied from pre-converted Vb (4 short8/thread)
        #pragma unroll
        for (int i = 0; i < 4; ++i) {
            int u = tid + i * 256;          // 0..1023
            int bm = u >> 9;
            int rem = u & 511;
            int r = rem >> 2, c8 = (rem & 3) * 8;
            short8 v = *(const short8*)(Vb + ((size_t)bm * RANKN + r) * DIMN + k0 + c8);
            *(short8*)&Bs[bm][r * PADK + c8] = v;
        }
        __syncthreads();

        short8 af[2], bfr[4];
        #pragma unroll
        for (int mi = 0; mi < 2; ++mi)
            af[mi] = *(const short8*)&As[(mi * 16 + lr) * PADK + q * 8];
        #pragma unroll
        for (int nj = 0; nj < 4; ++nj)
            bfr[nj] = *(const short8*)&Bs[mat][(wn + nj * 16 + lr) * PADK + q * 8];

        #pragma unroll
        for (int mi = 0; mi < 2; ++mi)
            #pragma unroll
            for (int nj = 0; nj < 4; ++nj)
                acc[mi][nj] = __builtin_amdgcn_mfma_f32_16x16x32_bf16(
                    af[mi], bfr[nj], acc[mi][nj], 0, 0, 0);
        __syncthreads();
    }

    // C/D layout: col=lane&15, row=(lane>>4)*4+reg (m89-verified)
    #pragma unroll
    for (int mi = 0; mi < 2; ++mi)
        #pragma unroll
        for (int nj = 0; nj < 4; ++nj)
            #pragma unroll
            for (int r = 0; r < 4; ++r) {
                int row = m0 + mi * 16 + q * 4 + r;
                int col = mat * RANKN + wn + nj * 16 + lr;
                xvb[(size_t)row * 256 + col] = f2bf(acc[mi][nj][r]);
            }
}

// ---------------------------------------------------------------------------
// Phase 2+3 fused: SINGLE-WAVE blocks, ZERO barriers. Grid 512 = (32
// d-chunks of 64) x 16 b, XCD-swizzled. One wave owns its 64 scan chains
// end-to-end:
//   per chunk (16 t): [issue xvb/x prefetch for chunk+1] -> 32 MFMA
//   (wx/wd = xv @ U^T, 16t x 64d) -> LDS transpose roundtrip (intra-wave
//   DS is in-order; lgkmcnt only, NO s_barrier) -> 16-step lane-local
//   chain -> lane-local gate -> dword stores (64 lanes = 256 B/instr).
// No __syncthreads anywhere => no vmcnt(0) drains: prefetched loads and
// stores stay in flight across chunk boundaries (the R3 structure drained
// everything at each of 66 barriers => ~6.7k cy/iter; work is ~1.2k).
// Unroll-by-2 swaps prefetch register sets statically (rule #20).
// LDS: 2 x 16 x 68 floats = 8.7 KB. ~310 VGPR -> 1 wave/SIMD, 2 blocks/CU.
// ---------------------------------------------------------------------------
__global__ __launch_bounds__(64, 1)
void fused_scan(const short* __restrict__ xvb, const float* __restrict__ x,
                const float* __restrict__ h0,
                const float* __restrict__ Ux, const float* __restrict__ Ud,
                const float* __restrict__ r_h, const float* __restrict__ r_delta,
                const float* __restrict__ bvec, const float* __restrict__ b_delta,
                const float* __restrict__ b_gate,
                float* __restrict__ obuf, float* __restrict__ hbuf) {
    __shared__ float wxs[CH * PADW];
    __shared__ float wds[CH * PADW];

    const int id   = blockIdx.x;        // 0..511
    const int xcd  = id & 7;
    const int slot = id >> 3;           // 0..63
    const int b  = xcd * 2 + (slot & 1);
    const int d0 = (slot >> 1) * 64;

    const int lane = threadIdx.x;       // 0..63
    const int lr = lane & 15;
    const int q  = lane >> 4;

    const int d = d0 + lane;
    const size_t xo = (size_t)b * DIMN + d;     // [B,D]-slab offset for lane

    // ---- one-time U fragment load + convert (B-operand layout: lane holds
    // U-row d0+nj*16+lr, k = ks*32 + q*8 .. +8)
    short8 uf[2][4][4];
    #pragma unroll
    for (int mat = 0; mat < 2; ++mat) {
        const float* Up = mat ? Ud : Ux;
        #pragma unroll
        for (int nj = 0; nj < 4; ++nj) {
            const size_t dd = (size_t)(d0 + nj * 16 + lr);
            #pragma unroll
            for (int ks = 0; ks < 4; ++ks) {
                const int k = ks * 32 + q * 8;
                float4 u0 = *(const float4*)&Up[dd * RANKN + k];
                float4 u1 = *(const float4*)&Up[dd * RANKN + k + 4];
                short8 v;
                v[0] = f2bf(u0.x); v[1] = f2bf(u0.y);
                v[2] = f2bf(u0.z); v[3] = f2bf(u0.w);
                v[4] = f2bf(u1.x); v[5] = f2bf(u1.y);
                v[6] = f2bf(u1.z); v[7] = f2bf(u1.w);
                uf[mat][nj][ks] = v;
            }
        }
    }

    // ---- per-lane scan constants + h0
    const float rh  = r_h[d];
    const float rd  = r_delta[d];
    const float bb  = bvec[d];
    const float bdl = b_delta[d];
    const float bg  = b_gate[d];
    float h = h0[xo];
    hbuf[xo] = h;                        // h[0] = h0

    // ---- prefetch chunk 0 (xvb A-fragments + x)
    short8 afA[2][4], afB[2][4];
    float  xqA[CH],  xqB[CH];
    {
        const size_t row = (size_t)lr * BBATCH + b;
        #pragma unroll
        for (int mat = 0; mat < 2; ++mat)
            #pragma unroll
            for (int ks = 0; ks < 4; ++ks)
                afA[mat][ks] = *(const short8*)
                    &xvb[row * 256 + mat * RANKN + ks * 32 + q * 8];
        #pragma unroll
        for (int s = 0; s < CH; ++s)
            xqA[s] = x[(size_t)s * BD + xo];
    }

    auto body = [&](int ch, short8 (&afU)[2][4], short8 (&afP)[2][4],
                    float (&xU)[CH], float (&xP)[CH]) {
        // ---- issue prefetch for chunk ch+1 FIRST (hidden under this chunk)
        if (ch < 63) {
            const size_t row = (size_t)((ch + 1) * CH + lr) * BBATCH + b;
            #pragma unroll
            for (int mat = 0; mat < 2; ++mat)
                #pragma unroll
                for (int ks = 0; ks < 4; ++ks)
                    afP[mat][ks] = *(const short8*)
                        &xvb[row * 256 + mat * RANKN + ks * 32 + q * 8];
            const size_t xb0 = (size_t)(ch + 1) * CH * BD + xo;
            #pragma unroll
            for (int s = 0; s < CH; ++s)
                xP[s] = x[xb0 + (size_t)s * BD];
        }

        // ---- MFMA fill: wx/wd[16t x 64d] -> LDS
        // C layout: row = q*4+r = t-in-chunk, col = nj*16+lr = d-in-chunk
        #pragma unroll
        for (int mat = 0; mat < 2; ++mat) {
            float* outp = mat ? wds : wxs;
            #pragma unroll
            for (int nj = 0; nj < 4; ++nj) {
                floatx4 acc = {};
                #pragma unroll
                for (int ks = 0; ks < 4; ++ks)
                    acc = __builtin_amdgcn_mfma_f32_16x16x32_bf16(
                        afU[mat][ks], uf[mat][nj][ks], acc, 0, 0, 0);
                #pragma unroll
                for (int r = 0; r < 4; ++r)
                    outp[(q * 4 + r) * PADW + nj * 16 + lr] = acc[r];
            }
        }
        // intra-wave DS ordering point (writes above, reads below; DS pipe
        // is in-order per wave — lgkmcnt(0) + memory clobber keeps the
        // compiler from reordering the reads above the writes)
        asm volatile("s_waitcnt lgkmcnt(0)" ::: "memory");

        // ---- transpose read: lane's chain operands for 16 steps
        float wxr[CH], wdr[CH];
        #pragma unroll
        for (int s = 0; s < CH; ++s) {
            wxr[s] = wxs[s * PADW + lane];
            wdr[s] = wds[s * PADW + lane];
        }

        // ---- chain + gate + stores, all lane-local
        const size_t tb = (size_t)ch * CH * BD + xo;
        #pragma unroll
        for (int s = 0; s < CH; ++s) {
            const float cand  = fast_tanh(rh * h + wxr[s] + bb);
            const float delta = fast_sigmoid(wdr[s] + rd * h + bdl);
            h = (1.0f - delta) * h + delta * cand;
            const float gg = h + xU[s] + bg;
            obuf[tb + (size_t)s * BD] = h * (gg * fast_sigmoid(gg));
            hbuf[tb + (size_t)(s + 1) * BD] = h;
        }
    };

    #pragma unroll 1
    for (int ii = 0; ii < 32; ++ii) {
        body(2 * ii,     afA, afB, xqA, xqB);
        body(2 * ii + 1, afB, afA, xqB, xqA);
    }
}

// ---------------------------------------------------------------------------
extern "C" void kernel_launch(void* const* d_in, const int* in_sizes, int n_in,
                              void* d_out, int out_size, void* d_ws, size_t ws_size,
                              hipStream_t stream) {
    const float* x       = (const float*)d_in[0];   // [T,B,D]
    const float* h0      = (const float*)d_in[1];   // [B,D]
    const float* U_x     = (const float*)d_in[2];   // [D,R]
    const float* V_x     = (const float*)d_in[3];   // [R,D]
    const float* U_d     = (const float*)d_in[4];   // [D,R]
    const float* V_d     = (const float*)d_in[5];   // [R,D]
    const float* r_h     = (const float*)d_in[6];
    const float* r_delta = (const float*)d_in[7];
    const float* bvec    = (const float*)d_in[8];
    const float* b_delta = (const float*)d_in[9];
    const float* b_gate  = (const float*)d_in[10];

    float* obuf = (float*)d_out;                    // output [T,B,D]
    float* hbuf = obuf + (size_t)TT * BD;           // h [T+1,B,D]
    short* xvb  = (short*)d_ws;                     // bf16 [16384][256]: xv|xd
    short* Vb   = xvb + (size_t)TT * BBATCH * 256;  // bf16 [256][2048]

    // Phase 0: one-time V -> bf16
    prep_vb<<<256, 256, 0, stream>>>(V_x, V_d, Vb);

    // Phase 1: both low-rank projections, x read once, bf16 out (R2 version).
    gemm_xv<<<TT * BBATCH / 32, 256, 0, stream>>>(x, Vb, xvb);

    // Phase 2+3: barrier-free single-wave fused GEMM + scan + gate.
    fused_scan<<<512, 64, 0, stream>>>(xvb, x, h0, U_x, U_d,
                                       r_h, r_delta, bvec, b_delta, b_gate,
                                       obuf, hbuf);
}

// Round 5
// 534.828 us; speedup vs baseline: 1.0838x; 1.0779x over previous
//
#include <hip/hip_runtime.h>

#define DIMN 2048
#define RANKN 128
#define TT 1024
#define BBATCH 16
#define BD (BBATCH * DIMN)   // 32768 elements per timestep slice
#define CH 16                // scan chunk length (t-steps)
#define PADW 68              // LDS row pitch in floats (<=2-way on all patterns)

typedef __attribute__((ext_vector_type(4))) float floatx4;
typedef __attribute__((ext_vector_type(8))) short short8;

// fp32 -> bf16 round-to-nearest-even on raw bits
__device__ __forceinline__ short f2bf(float f) {
    unsigned u = __float_as_uint(f);
    unsigned r = (u + 0x7FFFu + ((u >> 16) & 1u)) >> 16;
    return (short)r;
}
__device__ __forceinline__ float fast_sigmoid(float z) {
    return 1.0f / (1.0f + __expf(-z));
}
__device__ __forceinline__ float fast_tanh(float z) {
    return 1.0f - 2.0f / (__expf(2.0f * z) + 1.0f);
}

// ---------------------------------------------------------------------------
// Prep: V_x|V_d -> bf16 Vb[256][2048] (rows 0..127 = V_x, 128..255 = V_d).
// ---------------------------------------------------------------------------
__global__ __launch_bounds__(256)
void prep_vb(const float* __restrict__ Vx, const float* __restrict__ Vd,
             short* __restrict__ Vb) {
    const int gid = blockIdx.x * 256 + threadIdx.x;     // 0..65535
    const size_t base = (size_t)gid * 8;
    const size_t half = (size_t)RANKN * DIMN;           // 262144
    const float* src = (base < half) ? Vx : Vd;
    const size_t off = (base < half) ? base : (base - half);
    float4 a = *(const float4*)(src + off);
    float4 c = *(const float4*)(src + off + 4);
    short8 v;
    v[0] = f2bf(a.x); v[1] = f2bf(a.y); v[2] = f2bf(a.z); v[3] = f2bf(a.w);
    v[4] = f2bf(c.x); v[5] = f2bf(c.y); v[6] = f2bf(c.z); v[7] = f2bf(c.w);
    *(short8*)(Vb + base) = v;
}

// ---------------------------------------------------------------------------
// Phase 1: xvb = x @ [V_x^T | V_d^T] as bf16 [16384][256]. (R2 version —
// the fastest measured variant.) M-tile 32 -> 512 blocks = 2/CU.
// ---------------------------------------------------------------------------
__global__ __launch_bounds__(256, 2)
void gemm_xv(const float* __restrict__ X, const short* __restrict__ Vb,
             short* __restrict__ xvb) {
    constexpr int PADK = 40;
    __shared__ short As[32 * PADK];
    __shared__ short Bs[2][128 * PADK];

    const int m0 = blockIdx.x * 32;
    const int tid = threadIdx.x;
    const int wave = tid >> 6;
    const int lane = tid & 63;
    const int lr = lane & 15;
    const int q  = lane >> 4;
    const int mat = wave >> 1;
    const int wn  = (wave & 1) * 64;

    floatx4 acc[2][4] = {};

    for (int k0 = 0; k0 < DIMN; k0 += 32) {
        {
            int r = tid >> 3, c = (tid & 7) * 4;
            float4 v = *(const float4*)(X + (size_t)(m0 + r) * DIMN + k0 + c);
            *(short4*)&As[r * PADK + c] =
                make_short4(f2bf(v.x), f2bf(v.y), f2bf(v.z), f2bf(v.w));
        }
        #pragma unroll
        for (int i = 0; i < 4; ++i) {
            int u = tid + i * 256;
            int bm = u >> 9;
            int rem = u & 511;
            int r = rem >> 2, c8 = (rem & 3) * 8;
            short8 v = *(const short8*)(Vb + ((size_t)bm * RANKN + r) * DIMN + k0 + c8);
            *(short8*)&Bs[bm][r * PADK + c8] = v;
        }
        __syncthreads();

        short8 af[2], bfr[4];
        #pragma unroll
        for (int mi = 0; mi < 2; ++mi)
            af[mi] = *(const short8*)&As[(mi * 16 + lr) * PADK + q * 8];
        #pragma unroll
        for (int nj = 0; nj < 4; ++nj)
            bfr[nj] = *(const short8*)&Bs[mat][(wn + nj * 16 + lr) * PADK + q * 8];

        #pragma unroll
        for (int mi = 0; mi < 2; ++mi)
            #pragma unroll
            for (int nj = 0; nj < 4; ++nj)
                acc[mi][nj] = __builtin_amdgcn_mfma_f32_16x16x32_bf16(
                    af[mi], bfr[nj], acc[mi][nj], 0, 0, 0);
        __syncthreads();
    }

    #pragma unroll
    for (int mi = 0; mi < 2; ++mi)
        #pragma unroll
        for (int nj = 0; nj < 4; ++nj)
            #pragma unroll
            for (int r = 0; r < 4; ++r) {
                int row = m0 + mi * 16 + q * 4 + r;
                int col = mat * RANKN + wn + nj * 16 + lr;
                xvb[(size_t)row * 256 + col] = f2bf(acc[mi][nj][r]);
            }
}

// ---------------------------------------------------------------------------
// Phase 2+3 fused: 3-wave role pipeline, LDS-flag sync, ZERO barriers in the
// main loop (R3 showed __syncthreads' vmcnt(0) drain poisons this loop; R4
// showed a single wave serializes all roles at ~8000 cy/chunk).
// Grid 512 blocks x 192 thr = 1536 waves = 6/CU:
//   wave0 (chain):    spin on cw -> 32 ds_read b32 -> free buf -> 16-step
//                     pure-VALU chain -> 16 ds_write h -> signal chp.
//   wave1 (producer): U frags staged once in LDS (keeps VGPR < 256);
//                     per chunk: 32 ds_read_b128 U + MFMA x32 on xvb frags
//                     (global-prefetched 1 chunk ahead) -> ds_write wx/wd
//                     -> signal cw.
//   wave2 (flusher):  spin on chp -> read h (b128) -> free h-buf -> gate ->
//                     coalesced float4 stores obuf/hbuf; x prefetched 1
//                     chunk ahead.
// Sync: monotonic volatile LDS counters. DS pipe is in-order per wave, so
// producer signals need only a compiler barrier; consumers signal "freed"
// after s_waitcnt lgkmcnt(0) (reads landed in regs).
// LDS: U 32KB + 3 dbuf arrays 25.5KB + counters = ~58KB -> 2 blocks/CU.
// Math is bit-identical to the passing R4 version.
// ---------------------------------------------------------------------------
#define SPIN(ctr, tgt) \
    while (((volatile int*)cnt)[ctr] < (tgt)) __builtin_amdgcn_s_sleep(1); \
    asm volatile("" ::: "memory");

#define SIGNAL(ctr, val) \
    asm volatile("" ::: "memory"); \
    if (lane == 0) ((volatile int*)cnt)[ctr] = (val);

#define SIGNAL_AFTER_READS(ctr, val) \
    asm volatile("s_waitcnt lgkmcnt(0)" ::: "memory"); \
    if (lane == 0) ((volatile int*)cnt)[ctr] = (val);

__global__ __launch_bounds__(192, 2)
void fused_scan(const short* __restrict__ xvb, const float* __restrict__ x,
                const float* __restrict__ h0,
                const float* __restrict__ Ux, const float* __restrict__ Ud,
                const float* __restrict__ r_h, const float* __restrict__ r_delta,
                const float* __restrict__ bvec, const float* __restrict__ b_delta,
                const float* __restrict__ b_gate,
                float* __restrict__ obuf, float* __restrict__ hbuf) {
    __shared__ float wxs[2][CH * PADW];
    __shared__ float wds[2][CH * PADW];
    __shared__ float hsh[2][CH * PADW];
    __shared__ short8 Ulds[2][4][4][64];    // [mat][nj][ks][lane] frags, 32KB
    __shared__ int cnt[4];                  // 0:cw 1:cwc 2:chp 3:chc

    const int id   = blockIdx.x;            // 0..511
    const int xcd  = id & 7;
    const int slot = id >> 3;
    const int b  = xcd * 2 + (slot & 1);
    const int d0 = (slot >> 1) * 64;

    const int tid  = threadIdx.x;
    const int wave = tid >> 6;
    const int lane = tid & 63;
    const int lr = lane & 15;
    const int q  = lane >> 4;

    if (tid == 0) { cnt[0] = 0; cnt[1] = 0; cnt[2] = 0; cnt[3] = 0; }
    __syncthreads();                        // the only barrier

    if (wave == 1) {
        // ---------------- producer ----------------
        // one-time: U fragments -> LDS (B-operand layout: lane holds U-row
        // d0+nj*16+lr, k = ks*32 + q*8 .. +8)
        #pragma unroll
        for (int mat = 0; mat < 2; ++mat) {
            const float* Up = mat ? Ud : Ux;
            #pragma unroll
            for (int nj = 0; nj < 4; ++nj) {
                const size_t dd = (size_t)(d0 + nj * 16 + lr);
                #pragma unroll
                for (int ks = 0; ks < 4; ++ks) {
                    const int k = ks * 32 + q * 8;
                    float4 u0 = *(const float4*)&Up[dd * RANKN + k];
                    float4 u1 = *(const float4*)&Up[dd * RANKN + k + 4];
                    short8 v;
                    v[0] = f2bf(u0.x); v[1] = f2bf(u0.y);
                    v[2] = f2bf(u0.z); v[3] = f2bf(u0.w);
                    v[4] = f2bf(u1.x); v[5] = f2bf(u1.y);
                    v[6] = f2bf(u1.z); v[7] = f2bf(u1.w);
                    Ulds[mat][nj][ks][lane] = v;
                }
            }
        }
        // prefetch xvb fragments for chunk 0 (A row m = t*BBATCH + b)
        short8 afp[2][4];
        {
            const size_t row = (size_t)lr * BBATCH + b;
            #pragma unroll
            for (int mat = 0; mat < 2; ++mat)
                #pragma unroll
                for (int ks = 0; ks < 4; ++ks)
                    afp[mat][ks] = *(const short8*)
                        &xvb[row * 256 + mat * RANKN + ks * 32 + q * 8];
        }
        for (int ch = 0; ch < 64; ++ch) {
            if (ch >= 2) { SPIN(1, ch - 1) }            // wx/wd buf free
            const int pb = ch & 1;
            #pragma unroll
            for (int mat = 0; mat < 2; ++mat) {
                float* outp = mat ? wds[pb] : wxs[pb];
                #pragma unroll
                for (int nj = 0; nj < 4; ++nj) {
                    floatx4 acc = {};
                    #pragma unroll
                    for (int ks = 0; ks < 4; ++ks)
                        acc = __builtin_amdgcn_mfma_f32_16x16x32_bf16(
                            afp[mat][ks], Ulds[mat][nj][ks][lane], acc, 0, 0, 0);
                    #pragma unroll
                    for (int r = 0; r < 4; ++r)
                        outp[(q * 4 + r) * PADW + nj * 16 + lr] = acc[r];
                }
            }
            SIGNAL(0, ch + 1)                           // wx/wd ready (DS in-order)
            if (ch < 63) {                              // prefetch next chunk
                const size_t row = (size_t)((ch + 1) * CH + lr) * BBATCH + b;
                #pragma unroll
                for (int mat = 0; mat < 2; ++mat)
                    #pragma unroll
                    for (int ks = 0; ks < 4; ++ks)
                        afp[mat][ks] = *(const short8*)
                            &xvb[row * 256 + mat * RANKN + ks * 32 + q * 8];
            }
        }
    } else if (wave == 0) {
        // ---------------- chain ----------------
        const int d = d0 + lane;
        const size_t xo = (size_t)b * DIMN + d;
        const float rh  = r_h[d];
        const float rd  = r_delta[d];
        const float bb  = bvec[d];
        const float bdl = b_delta[d];
        float h = h0[xo];

        for (int ch = 0; ch < 64; ++ch) {
            SPIN(0, ch + 1)                             // wx/wd ready
            const int pb = ch & 1;
            float wxr[CH], wdr[CH];
            #pragma unroll
            for (int s = 0; s < CH; ++s) {
                wxr[s] = wxs[pb][s * PADW + lane];
                wdr[s] = wds[pb][s * PADW + lane];
            }
            SIGNAL_AFTER_READS(1, ch + 1)               // free wx/wd buf
            if (ch >= 2) { SPIN(3, ch - 1) }            // h buf free
            #pragma unroll
            for (int s = 0; s < CH; ++s) {
                const float cand  = fast_tanh(rh * h + wxr[s] + bb);
                const float delta = fast_sigmoid(wdr[s] + rd * h + bdl);
                h = (1.0f - delta) * h + delta * cand;
                hsh[pb][s * PADW + lane] = h;
            }
            SIGNAL(2, ch + 1)                           // h ready (DS in-order)
        }
    } else {
        // ---------------- flusher ----------------
        const int dq  = lane & 15;
        const int tof = lane >> 4;
        const size_t xoffF = (size_t)b * DIMN + d0 + dq * 4;
        const float4 bg4 = *(const float4*)&b_gate[d0 + dq * 4];
        {   // h[0] = h0 (d-contiguous float4 copy)
            const int dl = d0 + lane;                   // 64 d's, but as f4:
            (void)dl;
            float4 hv = *(const float4*)&h0[(size_t)b * DIMN + d0 + dq * 4
                                            + (size_t)tof * 0];
            if (tof == 0)
                *(float4*)&hbuf[(size_t)b * DIMN + d0 + dq * 4] = hv;
        }
        float4 xpre[4];
        #pragma unroll
        for (int jj = 0; jj < 4; ++jj)
            xpre[jj] = *(const float4*)&x[(size_t)(jj * 4 + tof) * BD + xoffF];

        for (int ch = 0; ch < 64; ++ch) {
            SPIN(2, ch + 1)                             // h ready
            const int pb = ch & 1;
            float4 hv[4];
            #pragma unroll
            for (int jj = 0; jj < 4; ++jj)
                hv[jj] = *(const float4*)&hsh[pb][(jj * 4 + tof) * PADW + dq * 4];
            SIGNAL_AFTER_READS(3, ch + 1)               // free h buf
            const int tb = ch * CH;
            #pragma unroll
            for (int jj = 0; jj < 4; ++jj) {
                const int t = jj * 4 + tof;
                const float4 xv = xpre[jj];
                float4 ov;
                float g0 = hv[jj].x + xv.x + bg4.x;
                ov.x = hv[jj].x * (g0 * fast_sigmoid(g0));
                float g1 = hv[jj].y + xv.y + bg4.y;
                ov.y = hv[jj].y * (g1 * fast_sigmoid(g1));
                float g2 = hv[jj].z + xv.z + bg4.z;
                ov.z = hv[jj].z * (g2 * fast_sigmoid(g2));
                float g3 = hv[jj].w + xv.w + bg4.w;
                ov.w = hv[jj].w * (g3 * fast_sigmoid(g3));
                *(float4*)&obuf[(size_t)(tb + t) * BD + xoffF] = ov;
                *(float4*)&hbuf[(size_t)(tb + t + 1) * BD + xoffF] = hv[jj];
            }
            if (ch < 63) {                              // prefetch next x
                const int tn = (ch + 1) * CH;
                #pragma unroll
                for (int jj = 0; jj < 4; ++jj)
                    xpre[jj] = *(const float4*)
                        &x[(size_t)(tn + jj * 4 + tof) * BD + xoffF];
            }
        }
    }
}

// ---------------------------------------------------------------------------
extern "C" void kernel_launch(void* const* d_in, const int* in_sizes, int n_in,
                              void* d_out, int out_size, void* d_ws, size_t ws_size,
                              hipStream_t stream) {
    const float* x       = (const float*)d_in[0];   // [T,B,D]
    const float* h0      = (const float*)d_in[1];   // [B,D]
    const float* U_x     = (const float*)d_in[2];   // [D,R]
    const float* V_x     = (const float*)d_in[3];   // [R,D]
    const float* U_d     = (const float*)d_in[4];   // [D,R]
    const float* V_d     = (const float*)d_in[5];   // [R,D]
    const float* r_h     = (const float*)d_in[6];
    const float* r_delta = (const float*)d_in[7];
    const float* bvec    = (const float*)d_in[8];
    const float* b_delta = (const float*)d_in[9];
    const float* b_gate  = (const float*)d_in[10];

    float* obuf = (float*)d_out;                    // output [T,B,D]
    float* hbuf = obuf + (size_t)TT * BD;           // h [T+1,B,D]
    short* xvb  = (short*)d_ws;                     // bf16 [16384][256]: xv|xd
    short* Vb   = xvb + (size_t)TT * BBATCH * 256;  // bf16 [256][2048]

    // Phase 0: one-time V -> bf16
    prep_vb<<<256, 256, 0, stream>>>(V_x, V_d, Vb);

    // Phase 1: both low-rank projections, x read once, bf16 out.
    gemm_xv<<<TT * BBATCH / 32, 256, 0, stream>>>(x, Vb, xvb);

    // Phase 2+3: 3-wave role-pipelined fused GEMM + scan + gate.
    fused_scan<<<512, 192, 0, stream>>>(xvb, x, h0, U_x, U_d,
                                        r_h, r_delta, bvec, b_delta, b_gate,
                                        obuf, hbuf);
}